// Round 6
// baseline (95.376 us; speedup 1.0000x reference)
//
#include <hip/hip_runtime.h>
#include <math.h>

// Tropical min-max matmul: out[b,o] = min_i max(x[b,i], w[i,o])
// B=1024, I=512, O=512, fp32.
//
// Round 6: no LDS, no workspace, one kernel.
//  Rationale: the harness poison-fills 268MB of d_ws every timed iteration
//  (~41us, saturates HBM, evicts all of L2+L3). Rounds 2-5's split-K
//  partials in d_ws both slowed that fill (R5: 41->47us) and got slowed by
//  it; inferred kernel time never matched pipe models. Inputs are only 3MB;
//  every operand access here is a 16-lane broadcast (x row chunks) or a
//  16-lane-replicated coalesced 256B read (w col chunks) -> serve straight
//  from L1/L2, skip the LDS pipe and all barriers.
//
//  Geometry: 16x64 tile, 256 thr, 1 row x 4 cols/thread, K=512 in-thread.
//  Grid (8,64) = 512 blocks = 2 blocks/CU = 8 waves/CU (2/SIMD TLP).
//  k16-unrolled: 20 independent float4 loads in flight per window
//  (~96 VGPR), then 48 min3/max VALU insts. VALU floor ~5-7us; L2-side
//  ~285MB @ 36TB/s ~ 8us. No __syncthreads anywhere.

__device__ __forceinline__ float4 vmax4(float s, float4 v) {
    return make_float4(fmaxf(s, v.x), fmaxf(s, v.y), fmaxf(s, v.z), fmaxf(s, v.w));
}
__device__ __forceinline__ float4 vmin3(float4 a, float4 b, float4 c) {
    return make_float4(fminf(fminf(a.x, b.x), c.x),
                       fminf(fminf(a.y, b.y), c.y),
                       fminf(fminf(a.z, b.z), c.z),
                       fminf(fminf(a.w, b.w), c.w));
}

__global__ __launch_bounds__(256, 2) void minmax_kernel(
    const float* __restrict__ x,    // [1024, 512]
    const float* __restrict__ w,    // [512, 512]
    float* __restrict__ out)        // [1024, 512]
{
    const int t  = threadIdx.x;
    const int tx = t & 15;                      // col group
    const int ty = t >> 4;                      // row within tile

    const int row = blockIdx.y * 16 + ty;       // 0..1023
    const int col = blockIdx.x * 64 + tx * 4;   // 0..508

    const float* xr = x + (size_t)row * 512;    // this thread's x row
    const float* wc = w + col;                  // this thread's w col base

    float4 acc = make_float4(INFINITY, INFINITY, INFINITY, INFINITY);

    for (int k = 0; k < 512; k += 16) {
        // ---- load phase: 4 x-float4 + 16 w-float4, all independent ----
        float4 xv[4];
        float4 wv[4][4];
#pragma unroll
        for (int q = 0; q < 4; ++q)
            xv[q] = *(const float4*)(xr + k + q * 4);
#pragma unroll
        for (int q = 0; q < 4; ++q)
#pragma unroll
            for (int j = 0; j < 4; ++j)
                wv[q][j] = *(const float4*)(wc + (size_t)(k + q * 4 + j) * 512);

        // ---- compute phase: 64 updates, min3-fused ----
#pragma unroll
        for (int q = 0; q < 4; ++q) {
            acc = vmin3(acc, vmax4(xv[q].x, wv[q][0]), vmax4(xv[q].y, wv[q][1]));
            acc = vmin3(acc, vmax4(xv[q].z, wv[q][2]), vmax4(xv[q].w, wv[q][3]));
        }
    }

    *(float4*)(out + (size_t)row * 512 + col) = acc;
}

extern "C" void kernel_launch(void* const* d_in, const int* in_sizes, int n_in,
                              void* d_out, int out_size, void* d_ws, size_t ws_size,
                              hipStream_t stream) {
    const float* x = (const float*)d_in[0];   // [1024, 512]
    const float* w = (const float*)d_in[1];   // [512, 512]
    float* out = (float*)d_out;               // [1024, 512]

    minmax_kernel<<<dim3(8, 64), 256, 0, stream>>>(x, w, out);
}